// Round 11
// baseline (260.885 us; speedup 1.0000x reference)
//
#include <hip/hip_runtime.h>
#include <hip/hip_bf16.h>
#include <math.h>

typedef __hip_bfloat16 bf16;
typedef __attribute__((ext_vector_type(4))) float f32x4;
typedef __attribute__((ext_vector_type(8))) short s16x8;

#define T_SEQ 2048
#define DIM   2048
#define NH    16
#define LAT   512
#define RD    64
#define TOPK  32

typedef const __attribute__((address_space(1))) void* gas_ptr;
typedef __attribute__((address_space(3))) void* las_ptr;

// ---------------------------------------------------------------------------
// Grouped GEMM descriptors.
// flags: 1 = RoPE epilogue (rotate col pairs (c, c+32), position = t0+row),
//        2 = column guard (col < N), 4 = fp32 output (C reinterpreted float*).
// ---------------------------------------------------------------------------
struct GGroup {
    const bf16* A; const bf16* BT; bf16* C;
    int K, lda, ldb, ldc;
    int tx, ty, nz;          // tiles in n, m, z
    long aZ, bZ, cZ;         // element strides per z
    int tiles;               // tx*ty*nz
    int flags, N, t0;
};
struct GPack { GGroup g[4]; int n; };

// ---------------------------------------------------------------------------
// MT x 64-tile grouped GEMM, BK=64, MT in {64,128,256}. 4 waves, wave =
// (MT/4) rows x 64 cols. XOR seg swizzle (r8/r9: stride 128B = 32 banks;
// staging permutes 16B segs by seg^(row&7) via the GLOBAL address, fragment
// reads un-permute -> 8 lanes/4-bank-group, conflict-free b128; verified r9:
// SQ_LDS_BANK_CONFLICT -> 0). MT=256 doubles MFMA per staged byte for
// density-poor shapes (Wo, small-K q~).
// ---------------------------------------------------------------------------
template<int MT>
__global__ __launch_bounds__(256)
void gemm_group64(GPack gp)
{
    constexpr int MI = MT / 64;          // i-frags per wave (1, 2 or 4)
    int b = blockIdx.x;
    int gi = 0;
    while (gi < gp.n - 1 && b >= gp.g[gi].tiles) { b -= gp.g[gi].tiles; ++gi; }
    const GGroup g = gp.g[gi];

    const int per_z = g.tx * g.ty;
    const int z   = b / per_z;
    const int rem = b - z * per_z;
    const int bx  = rem % g.tx;
    const int by  = rem / g.tx;

    const bf16* A  = g.A  + (size_t)z * g.aZ;
    const bf16* BT = g.BT + (size_t)z * g.bZ;
    bf16*       C  = g.C  + (size_t)z * g.cZ;

    __shared__ bf16 aL[MT * 64];
    __shared__ bf16 bL[64 * 64];

    const int tid  = threadIdx.x;
    const int wave = tid >> 6;
    const int lane = tid & 63;
    const int quad = lane >> 4;
    const int l16  = lane & 15;

    const int tile_m = by * MT;
    const int tile_n = bx * 64;
    const int wrow = wave * (MT / 4);

    const int lrow = lane >> 3;
    const int lke  = (((lane & 7) ^ lrow) * 8);      // XOR-swizzled seg
    const int sw   = l16 & 7;

    f32x4 acc[MI][4] = {};

    for (int k0 = 0; k0 < g.K; k0 += 64) {
#pragma unroll
        for (int p = 0; p < 2 * MI; ++p) {
            const int R = (wave * 2 * MI + p) * 8;
            const bf16* src = A + (size_t)(tile_m + R + lrow) * g.lda + k0 + lke;
            __builtin_amdgcn_global_load_lds((gas_ptr)src, (las_ptr)(aL + R * 64), 16, 0, 0);
        }
#pragma unroll
        for (int p = 0; p < 2; ++p) {
            const int R = (wave * 2 + p) * 8;
            const bf16* src = BT + (size_t)(tile_n + R + lrow) * g.ldb + k0 + lke;
            __builtin_amdgcn_global_load_lds((gas_ptr)src, (las_ptr)(bL + R * 64), 16, 0, 0);
        }
        __syncthreads();

#pragma unroll
        for (int ks = 0; ks < 2; ++ks) {
            s16x8 af[MI], bfr[4];
#pragma unroll
            for (int i = 0; i < MI; ++i)
                af[i] = *(const s16x8*)(&aL[(wrow + i * 16 + l16) * 64 +
                                            (((ks * 4 + quad) ^ sw) * 8)]);
#pragma unroll
            for (int j = 0; j < 4; ++j)
                bfr[j] = *(const s16x8*)(&bL[(j * 16 + l16) * 64 +
                                             (((ks * 4 + quad) ^ sw) * 8)]);

#pragma unroll
            for (int i = 0; i < MI; ++i)
#pragma unroll
                for (int j = 0; j < 4; ++j)
                    acc[i][j] = __builtin_amdgcn_mfma_f32_16x16x32_bf16(
                        af[i], bfr[j], acc[i][j], 0, 0, 0);
        }
        __syncthreads();
    }

    // D mapping: col = lane&15, row = (lane>>4)*4 + reg   [m89-verified]
    if (g.flags & 1) {
#pragma unroll
        for (int jp = 0; jp < 2; ++jp) {
            const int colL = tile_n + jp * 16 + l16;
            if ((g.flags & 2) && colL >= g.N) continue;
            const float fr = powf(10000.f, -(float)(jp * 16 + l16) / 32.f);
#pragma unroll
            for (int i = 0; i < MI; ++i) {
#pragma unroll
                for (int r = 0; r < 4; ++r) {
                    const int row = tile_m + wrow + i * 16 + quad * 4 + r;
                    float sv, cv;
                    sincosf((float)(g.t0 + row) * fr, &sv, &cv);
                    const float x0 = acc[i][jp][r];
                    const float x1 = acc[i][jp + 2][r];
                    C[(size_t)row * g.ldc + colL]      = __float2bfloat16(x0 * cv - x1 * sv);
                    C[(size_t)row * g.ldc + colL + 32] = __float2bfloat16(x1 * cv + x0 * sv);
                }
            }
        }
    } else if (g.flags & 4) {
        float* Cf = (float*)C;
#pragma unroll
        for (int j = 0; j < 4; ++j) {
            const int col = tile_n + j * 16 + l16;
#pragma unroll
            for (int i = 0; i < MI; ++i)
#pragma unroll
                for (int r = 0; r < 4; ++r) {
                    const int row = tile_m + wrow + i * 16 + quad * 4 + r;
                    Cf[(size_t)row * g.ldc + col] = acc[i][j][r];
                }
        }
    } else {
#pragma unroll
        for (int j = 0; j < 4; ++j) {
            const int col = tile_n + j * 16 + l16;
            if ((g.flags & 2) && col >= g.N) continue;
#pragma unroll
            for (int i = 0; i < MI; ++i)
#pragma unroll
                for (int r = 0; r < 4; ++r) {
                    const int row = tile_m + wrow + i * 16 + quad * 4 + r;
                    C[(size_t)row * g.ldc + col] = __float2bfloat16(acc[i][j][r]);
                }
        }
    }
}

// ---------------------------------------------------------------------------
// Unified prep kernel: per-descriptor mode 0 = transpose+convert (fp32 RxC ->
// bf16 CxR, 32x33 LDS tiles); mode 1 = straight fp32->bf16 convert (R = elem
// count, 2048 elems per tile, 8 per thread).
// ---------------------------------------------------------------------------
struct TDesc { const float* src; bf16* dst; int R; int C; int tiles; int ctiles; int mode; };
struct TPack { TDesc d[10]; int n; };

__global__ __launch_bounds__(256)
void prep_batch(TPack p)
{
    int b = blockIdx.x;
    int mi = 0;
    while (mi < p.n - 1 && b >= p.d[mi].tiles) { b -= p.d[mi].tiles; ++mi; }
    const TDesc d = p.d[mi];

    if (d.mode == 1) {
        size_t base = ((size_t)b * 256 + threadIdx.x) * 8;
        if (base >= (size_t)d.R) return;
        const float4 a  = *(const float4*)(d.src + base);
        const float4 b4 = *(const float4*)(d.src + base + 4);
        bf16 t[8];
        t[0] = __float2bfloat16(a.x);  t[1] = __float2bfloat16(a.y);
        t[2] = __float2bfloat16(a.z);  t[3] = __float2bfloat16(a.w);
        t[4] = __float2bfloat16(b4.x); t[5] = __float2bfloat16(b4.y);
        t[6] = __float2bfloat16(b4.z); t[7] = __float2bfloat16(b4.w);
        *(uint4*)(d.dst + base) = *(uint4*)t;
        return;
    }

    const int tr = b / d.ctiles, tc = b % d.ctiles;
    const int r0 = tr * 32, c0 = tc * 32;

    __shared__ float lds[32][33];
    const int tx = threadIdx.x & 31, ty = threadIdx.x >> 5;
#pragma unroll
    for (int i = 0; i < 4; ++i)
        lds[ty * 4 + i][tx] = d.src[(size_t)(r0 + ty * 4 + i) * d.C + c0 + tx];
    __syncthreads();
#pragma unroll
    for (int i = 0; i < 4; ++i)
        d.dst[(size_t)(c0 + ty * 4 + i) * d.R + r0 + tx] =
            __float2bfloat16(lds[tx][ty * 4 + i]);
}

// ---------------------------------------------------------------------------
// MLA-absorbed sparse attention (round-5 proven). One block per query t.
// ---------------------------------------------------------------------------
__global__ __launch_bounds__(256)
void attn_mla(const bf16* __restrict__ qt,   // [rows][8192] chunk (q~ per head)
              const bf16* __restrict__ qr,   // [rows][1024] chunk (rope'd)
              const bf16* __restrict__ xw,   // [2048][1024], ckv = cols 512..1023
              const bf16* __restrict__ kr,   // [2048][64] (rope'd)
              const int*  __restrict__ topk, // [2048][32]
              bf16* __restrict__ U,          // [rows][8192]
              int t0)
{
    __shared__ short ckv_s[32 * 520];
    __shared__ short qt_s[16 * 520];
    __shared__ short kr_s[32 * 72];
    __shared__ short qr_s[16 * 72];
    __shared__ short P_s[4][16 * 40];
    __shared__ int   idx_s[32];

    const int tl   = blockIdx.x;
    const int tg   = t0 + tl;
    const int tid  = threadIdx.x;
    const int wv   = tid >> 6;
    const int lane = tid & 63;
    const int quad = lane >> 4;
    const int l16  = lane & 15;

    if (tid < 32) {
        int j = topk[(size_t)tg * TOPK + tid];
        idx_s[tid] = (j < 0 || j >= T_SEQ) ? 0 : j;
    }
    __syncthreads();

#pragma unroll
    for (int i = 0; i < 8; ++i) {
        const int row = wv * 8 + i;
        const int j = idx_s[row];
        __builtin_amdgcn_global_load_lds(
            (gas_ptr)(xw + (size_t)j * 1024 + 512 + lane * 8),
            (las_ptr)(ckv_s + row * 520), 16, 0, 0);
    }
#pragma unroll
    for (int i = 0; i < 4; ++i) {
        const int seg = wv * 4 + i;
        __builtin_amdgcn_global_load_lds(
            (gas_ptr)(qt + (size_t)tl * 8192 + seg * 512 + lane * 8),
            (las_ptr)(qt_s + seg * 520), 16, 0, 0);
    }
    {
        const int row = tid >> 3, seg = tid & 7;
        const int j = idx_s[row];
        *(uint4*)(kr_s + row * 72 + seg * 8) =
            *(const uint4*)(kr + (size_t)j * RD + seg * 8);
    }
    if (tid < 128) {
        const int head = tid >> 3, seg = tid & 7;
        *(uint4*)(qr_s + head * 72 + seg * 8) =
            *(const uint4*)(qr + (size_t)tl * 1024 + head * 64 + seg * 8);
    }
    __syncthreads();

    f32x4 sc[2] = {};
#pragma unroll
    for (int ks = 0; ks < 16; ++ks) {
        s16x8 a  = *(const s16x8*)(qt_s + l16 * 520 + ks * 32 + quad * 8);
        s16x8 b0 = *(const s16x8*)(ckv_s + l16 * 520 + ks * 32 + quad * 8);
        s16x8 b1 = *(const s16x8*)(ckv_s + (16 + l16) * 520 + ks * 32 + quad * 8);
        sc[0] = __builtin_amdgcn_mfma_f32_16x16x32_bf16(a, b0, sc[0], 0, 0, 0);
        sc[1] = __builtin_amdgcn_mfma_f32_16x16x32_bf16(a, b1, sc[1], 0, 0, 0);
    }
#pragma unroll
    for (int ks = 0; ks < 2; ++ks) {
        s16x8 a  = *(const s16x8*)(qr_s + l16 * 72 + ks * 32 + quad * 8);
        s16x8 b0 = *(const s16x8*)(kr_s + l16 * 72 + ks * 32 + quad * 8);
        s16x8 b1 = *(const s16x8*)(kr_s + (16 + l16) * 72 + ks * 32 + quad * 8);
        sc[0] = __builtin_amdgcn_mfma_f32_16x16x32_bf16(a, b0, sc[0], 0, 0, 0);
        sc[1] = __builtin_amdgcn_mfma_f32_16x16x32_bf16(a, b1, sc[1], 0, 0, 0);
    }

    const float scale = 0.0721687836487032f;   // 1/sqrt(192)
    float inv[4];
    short* pw = P_s[wv];
#pragma unroll
    for (int r = 0; r < 4; ++r) {
        float s0 = sc[0][r] * scale, s1 = sc[1][r] * scale;
        float mx = fmaxf(s0, s1);
#pragma unroll
        for (int off = 1; off < 16; off <<= 1) mx = fmaxf(mx, __shfl_xor(mx, off));
        float p0 = __expf(s0 - mx), p1 = __expf(s1 - mx);
        float l = p0 + p1;
#pragma unroll
        for (int off = 1; off < 16; off <<= 1) l += __shfl_xor(l, off);
        inv[r] = 1.f / l;
        pw[(quad * 4 + r) * 40 + l16]      = __builtin_bit_cast(short, __float2bfloat16(p0));
        pw[(quad * 4 + r) * 40 + 16 + l16] = __builtin_bit_cast(short, __float2bfloat16(p1));
    }

    s16x8 ap = *(const s16x8*)(pw + l16 * 40 + quad * 8);
#pragma unroll
    for (int tt = 0; tt < 8; ++tt) {
        const int n0 = wv * 128 + tt * 16;
        s16x8 b;
#pragma unroll
        for (int j = 0; j < 8; ++j)
            b[j] = ckv_s[(quad * 8 + j) * 520 + n0 + l16];
        f32x4 u = {};
        u = __builtin_amdgcn_mfma_f32_16x16x32_bf16(ap, b, u, 0, 0, 0);
#pragma unroll
        for (int r = 0; r < 4; ++r)
            U[(size_t)tl * 8192 + (quad * 4 + r) * 512 + n0 + l16] =
                __float2bfloat16(u[r] * inv[r]);
    }
}

// ---------------------------------------------------------------------------
extern "C" void kernel_launch(void* const* d_in, const int* in_sizes, int n_in,
                              void* d_out, int out_size, void* d_ws, size_t ws_size,
                              hipStream_t stream)
{
    const float* x    = (const float*)d_in[0];
    const float* Wqd  = (const float*)d_in[1];
    const float* Wqu  = (const float*)d_in[2];
    const float* Wqr  = (const float*)d_in[3];
    const float* Wkvd = (const float*)d_in[4];
    const float* Wku  = (const float*)d_in[5];
    const float* Wvu  = (const float*)d_in[6];
    const float* Wkr  = (const float*)d_in[7];
    const float* Wo   = (const float*)d_in[8];
    const int*   topk = (const int*)d_in[9];
    float* out = (float*)d_out;

    const size_t KB = 1024;
    char* ws = (char*)d_ws;
    const bool flat = ws_size >= (size_t)128000 * KB;
    const int  TCH  = flat ? 2048 : 512;
    const int  NCH  = T_SEQ / TCH;

    size_t oXB, oWxT, oWkrT, oWquT, oWkub, oWqrT, oWvuT, oQ, oXW, oKR,
           oQR, oO, oWoT, oQT, oU;
    if (flat) {
        oXB = 0;       oWxT = 8192;   oWkrT = 12288; oWquT = 12544;
        oWkub = 14592; oWqrT = 16640; oWvuT = 17664; oQ = 19712;
        oXW = 27904;   oKR = 32000;   oQR = 32256;   oO = 36352;
        oWoT = 44544;  oQT = 52736;   oU = 85504;
    } else {
        oXW = 0;       oKR = 4096;    oWquT = 4352;  oWkub = 6400;
        oWqrT = 8448;  oWvuT = 9472;  oO = 11520;    oXB = 19712;
        oWxT = 27904;  oWkrT = 32000; oQ = 19712;    oQT = 21760;
        oQR = 29952;   oU = 30976;    oWoT = 21760;
    }
    bf16* xb   = (bf16*)(ws + oXB * KB);
    bf16* WxT  = (bf16*)(ws + oWxT * KB);
    bf16* WkrT = (bf16*)(ws + oWkrT * KB);
    bf16* WquT = (bf16*)(ws + oWquT * KB);
    bf16* Wkub = (bf16*)(ws + oWkub * KB);
    bf16* WqrT = (bf16*)(ws + oWqrT * KB);
    bf16* WvuT = (bf16*)(ws + oWvuT * KB);
    bf16* qB   = (bf16*)(ws + oQ * KB);
    bf16* xw   = (bf16*)(ws + oXW * KB);
    bf16* kr   = (bf16*)(ws + oKR * KB);
    bf16* qrC  = (bf16*)(ws + oQR * KB);
    bf16* o    = (bf16*)(ws + oO * KB);
    bf16* WoT  = (bf16*)(ws + oWoT * KB);
    bf16* qtC  = (bf16*)(ws + oQT * KB);
    bf16* uC   = (bf16*)(ws + oU * KB);

    dim3 blk(256);

    // Phase A (one dispatch): converts (x, Wku) + transposes (all weights)
    {
        TPack p;
        p.d[0] = { x,    xb,   T_SEQ * DIM, 0, T_SEQ * DIM / 2048, 0, 1 };
        p.d[1] = { Wku,  Wkub, LAT * DIM,   0, LAT * DIM / 2048,   0, 1 };
        p.d[2] = { Wqd,  WxT,                   DIM, LAT,  (DIM/32)*(LAT/32),  LAT/32,  0 };
        p.d[3] = { Wkvd, WxT + (size_t)LAT*DIM, DIM, LAT,  (DIM/32)*(LAT/32),  LAT/32,  0 };
        p.d[4] = { Wkr,  WkrT,                  DIM, RD,   (DIM/32)*(RD/32),   RD/32,   0 };
        p.d[5] = { Wqr,  WqrT,                  LAT, 1024, (LAT/32)*(1024/32), 1024/32, 0 };
        p.d[6] = { Wvu,  WvuT,                  LAT, DIM,  (LAT/32)*(DIM/32),  DIM/32,  0 };
        p.d[7] = { Wqu,  WquT,                  LAT, DIM,  (LAT/32)*(DIM/32),  DIM/32,  0 };
        p.n = 8;
        int tot = 0;
        for (int i = 0; i < p.n; ++i) tot += p.d[i].tiles;
        if (flat) {
            p.d[8] = { Wo, WoT, DIM, DIM, (DIM/32)*(DIM/32), DIM/32, 0 };
            p.n = 9; tot += p.d[8].tiles;
        }
        prep_batch<<<tot, blk, 0, stream>>>(p);
    }

    // Phase B (64x64 tiles -> 544 blocks): xw = xb@WxT^T | kr (rope)
    {
        GPack gp;
        gp.g[0] = { xb, WxT,  xw, DIM, DIM, DIM, 1024, 1024/64, T_SEQ/64, 1,
                    0, 0, 0, (1024/64)*(T_SEQ/64), 0, 1024, 0 };
        gp.g[1] = { xb, WkrT, kr, DIM, DIM, DIM, RD,   1,       T_SEQ/64, 1,
                    0, 0, 0, T_SEQ/64, 1 /*rope*/, RD, 0 };
        gp.n = 2;
        gemm_group64<64><<<gp.g[0].tiles + gp.g[1].tiles, blk, 0, stream>>>(gp);
    }

    // Phase C/D per chunk: {q, qr(+rope)} (MT=128) -> q~ (MT=256, z=16,
    // K=128) -> attention -> U-projection (MT=128)
    for (int c = 0; c < NCH; ++c) {
        const int t0 = c * TCH;
        bf16* q  = flat ? qB  + (size_t)t0 * 2048 : qB;
        bf16* qt = flat ? qtC + (size_t)t0 * 8192 : qtC;
        bf16* qr = flat ? qrC + (size_t)t0 * 1024 : qrC;
        bf16* U  = flat ? uC  + (size_t)t0 * 8192 : uC;
        const bf16* xwc = xw + (size_t)t0 * 1024;

        {
            GPack gp;
            gp.g[0] = { xwc, WquT, q,  LAT, 1024, LAT, 2048, 2048/64, TCH/128, 1,
                        0, 0, 0, (2048/64)*(TCH/128), 0, 2048, 0 };
            gp.g[1] = { xwc, WqrT, qr, LAT, 1024, LAT, 1024, 1024/64, TCH/128, 1,
                        0, 0, 0, (1024/64)*(TCH/128), 1 /*rope*/, 1024, t0 };
            gp.n = 2;
            gemm_group64<128><<<gp.g[0].tiles + gp.g[1].tiles, blk, 0, stream>>>(gp);
        }
        {
            GPack gp;  // q~_h = q_h @ Wku_h^T : M=TCH, N=512, K=128, z=16
            gp.g[0] = { q, Wkub, qt, 128, 2048, 2048, 8192, 512/64, TCH/256, NH,
                        128, 128, 512, (512/64)*(TCH/256)*NH, 0, 512, 0 };
            gp.n = 1;
            gemm_group64<256><<<gp.g[0].tiles, blk, 0, stream>>>(gp);
        }
        attn_mla<<<TCH, blk, 0, stream>>>(qt, qr, xw, kr, topk, U, t0);
        {
            GPack gp;
            gp.g[0] = { U, WvuT, o + (size_t)t0 * DIM, LAT, 8192, LAT, DIM,
                        2, TCH/128, NH, 512, (long)128*LAT, 128,
                        2*(TCH/128)*NH, 0, 128, 0 };
            gp.n = 1;
            gemm_group64<128><<<gp.g[0].tiles, blk, 0, stream>>>(gp);
        }
    }

    // Phase E: out = o @ WoT^T (fp32), MT=256 -> 256 blocks of 256x64
    if (!flat) {
        TPack p;
        p.d[0] = { Wo, WoT, DIM, DIM, (DIM/32)*(DIM/32), DIM/32, 0 };
        p.n = 1;
        prep_batch<<<p.d[0].tiles, blk, 0, stream>>>(p);
    }
    {
        GPack gp;
        gp.g[0] = { o, WoT, (bf16*)out, DIM, DIM, DIM, DIM,
                    DIM/64, T_SEQ/256, 1, 0, 0, 0,
                    (DIM/64)*(T_SEQ/256), 4 /*fp32*/, DIM, 0 };
        gp.n = 1;
        gemm_group64<256><<<gp.g[0].tiles, blk, 0, stream>>>(gp);
    }
}